// Round 2
// baseline (640.965 us; speedup 1.0000x reference)
//
#include <hip/hip_runtime.h>

typedef _Float16 f16x8 __attribute__((ext_vector_type(8)));
typedef _Float16 f16x4 __attribute__((ext_vector_type(4)));
typedef float    f32x4 __attribute__((ext_vector_type(4)));

#define MFMA16(a,b,c) __builtin_amdgcn_mfma_f32_16x16x32_f16((a),(b),(c),0,0,0)

constexpr int Bc  = 8;
constexpr int Sc  = 1024;
constexpr int Hc  = 512;
constexpr int NHc = 8;
constexpr int HDc = 64;

// ---------------------------------------------------------------------------
// Stage 0: fp32 -> fp16 convert of hs and the three W matrices (concatenated).
// hs16: [8192][512], w16: [1536][512] (rows 0-511 Wq, 512-1023 Wk, 1024- Wv).
// ---------------------------------------------------------------------------
__global__ __launch_bounds__(256) void cvt_f16(
    const float* __restrict__ hs,
    const float* __restrict__ wq, const float* __restrict__ wk,
    const float* __restrict__ wv,
    _Float16* __restrict__ hs16, _Float16* __restrict__ w16)
{
    const size_t i4  = (size_t)blockIdx.x * 256 + threadIdx.x;  // float4 index
    const size_t HS4 = (size_t)Bc * Sc * Hc / 4;   // 1,048,576
    const size_t W4  = (size_t)Hc * Hc / 4;        // 65,536
    float4 v;
    _Float16* dst;
    if (i4 < HS4) {
        v = ((const float4*)hs)[i4];
        dst = hs16 + i4 * 4;
    } else {
        const size_t j = i4 - HS4;
        const int z = (int)(j / W4);
        const size_t o = j - (size_t)z * W4;
        const float* src = (z == 0) ? wq : (z == 1) ? wk : wv;
        v = ((const float4*)src)[o];
        dst = w16 + j * 4;
    }
    f16x4 h;
    h[0] = (_Float16)v.x; h[1] = (_Float16)v.y;
    h[2] = (_Float16)v.z; h[3] = (_Float16)v.w;
    *(f16x4*)dst = h;
}

// ---------------------------------------------------------------------------
// Stage 1: fused QKV GEMM, m97-style. C[m][n] = hs16[m][:] . w16[n][:] + b[n]
// M=8192, N=1536, K=512. 128x128 tiles, BK=64, global_load_lds width-16.
// Q,K -> [BH][S][64] fp16;  V -> transposed [BH][64][S] fp16.
// ---------------------------------------------------------------------------
__global__ __launch_bounds__(256) void qkv_gemm(
    const _Float16* __restrict__ A,   // [8192][512]
    const _Float16* __restrict__ Bm,  // [1536][512]
    const float* __restrict__ bq, const float* __restrict__ bk,
    const float* __restrict__ bv,
    _Float16* __restrict__ qws, _Float16* __restrict__ kws,
    _Float16* __restrict__ vws)
{
    __shared__ __align__(16) _Float16 As[128 * 64];
    __shared__ __align__(16) _Float16 Bs[128 * 64];

    const int m0 = blockIdx.x * 128;   // 64
    const int n0 = blockIdx.y * 128;   // 12
    const int tid  = threadIdx.x;
    const int lane = tid & 63;
    const int w    = tid >> 6;
    const int l15  = lane & 15;
    const int quad = lane >> 4;
    const int wm   = (w >> 1) * 64;
    const int wn   = (w & 1) * 64;

    f32x4 acc[4][4] = {};

    const int srow = tid >> 3;         // 0..31
    const int scol = (tid & 7) * 8;    // fp16 units

    for (int k0 = 0; k0 < 512; k0 += 64) {
        __syncthreads();               // WAR: frag reads of prev tile done
#pragma unroll
        for (int j = 0; j < 4; ++j) {
            const _Float16* ga = A  + (size_t)(m0 + srow + 32 * j) * 512 + k0 + scol;
            const _Float16* gb = Bm + (size_t)(n0 + srow + 32 * j) * 512 + k0 + scol;
            __builtin_amdgcn_global_load_lds(
                (const __attribute__((address_space(1))) void*)ga,
                (__attribute__((address_space(3))) void*)(As + tid * 8 + j * 2048),
                16, 0, 0);
            __builtin_amdgcn_global_load_lds(
                (const __attribute__((address_space(1))) void*)gb,
                (__attribute__((address_space(3))) void*)(Bs + tid * 8 + j * 2048),
                16, 0, 0);
        }
        __syncthreads();               // RAW: vmcnt(0) drained before barrier
#pragma unroll
        for (int ks = 0; ks < 2; ++ks) {
            f16x8 af[4], bf[4];
#pragma unroll
            for (int i = 0; i < 4; ++i) {
                af[i] = *(const f16x8*)&As[(wm + i * 16 + l15) * 64 + ks * 32 + quad * 8];
                bf[i] = *(const f16x8*)&Bs[(wn + i * 16 + l15) * 64 + ks * 32 + quad * 8];
            }
#pragma unroll
            for (int mb = 0; mb < 4; ++mb)
#pragma unroll
                for (int nb = 0; nb < 4; ++nb)
                    acc[mb][nb] = MFMA16(af[mb], bf[nb], acc[mb][nb]);
        }
    }

    // Epilogue. zsel uniform per block (128 | 512).
    const int zsel = n0 >> 9;
    const float* bias = (zsel == 0) ? bq : (zsel == 1) ? bk : bv;
#pragma unroll
    for (int nb = 0; nb < 4; ++nb) {
        const int n  = n0 + wn + nb * 16 + l15;
        const int nn = n & 511;
        const int h  = nn >> 6;
        const int hd = nn & 63;
        const float bvv = bias[nn];
#pragma unroll
        for (int mb = 0; mb < 4; ++mb) {
            const int m = m0 + wm + mb * 16 + quad * 4;   // +rr, rr=0..3
            const int b = m >> 10;
            const int s = m & 1023;
            if (zsel == 2) {
                f16x4 t;
#pragma unroll
                for (int rr = 0; rr < 4; ++rr)
                    t[rr] = (_Float16)(acc[mb][nb][rr] + bvv);
                *(f16x4*)&vws[((size_t)(b * NHc + h) * HDc + hd) * Sc + s] = t;
            } else {
                _Float16* dst = (zsel == 0 ? qws : kws)
                              + ((size_t)(b * NHc + h) * Sc + s) * HDc + hd;
#pragma unroll
                for (int rr = 0; rr < 4; ++rr)
                    dst[(size_t)rr * HDc] = (_Float16)(acc[mb][nb][rr] + bvv);
            }
        }
    }
}

// ---------------------------------------------------------------------------
// Stage 2: flash attention with rel_2d_pos bias + additive mask.
// Block: 64 q rows (4 waves x 16). NO inner barriers: lds_p is per-wave, so
// waves free-run and hide the rel-bias HBM latency; rel tile kt+1 is
// register-prefetched while tile kt is consumed.
// ---------------------------------------------------------------------------
__global__ __launch_bounds__(256) void attn(
    const _Float16* __restrict__ qws, const _Float16* __restrict__ kws,
    const _Float16* __restrict__ vws, const float* __restrict__ rel,
    const float* __restrict__ mask, float* __restrict__ out)
{
    const int qt = blockIdx.x;      // 0..15
    const int bh = blockIdx.y;      // 0..63
    const int b  = bh >> 3;
    const int h  = bh & 7;
    const int tid  = threadIdx.x;
    const int w    = tid >> 6;
    const int lane = tid & 63;
    const int l15  = lane & 15;
    const int quad = lane >> 4;
    const int q0w  = qt * 64 + w * 16;

    __shared__ __align__(16) _Float16 lds_p[4][16][72];  // per-wave slice

    const _Float16* qh = qws + (size_t)bh * Sc * HDc;
    const _Float16* kh = kws + (size_t)bh * Sc * HDc;
    const _Float16* vh = vws + (size_t)bh * HDc * Sc;
    const float* relh  = rel + (size_t)bh * Sc * Sc;
    const float* maskb = mask + (size_t)b * Sc;

    f16x8 qf0 = *(const f16x8*)(qh + (size_t)(q0w + l15) * HDc + quad * 8);
    f16x8 qf1 = *(const f16x8*)(qh + (size_t)(q0w + l15) * HDc + 32 + quad * 8);

    float m_run[4], l_run[4];
    f32x4 o[4] = {};
#pragma unroll
    for (int rj = 0; rj < 4; ++rj) { m_run[rj] = -1e30f; l_run[rj] = 0.f; }

    // prefetch rel tile 0 into registers
    float rbuf[16];
#pragma unroll
    for (int nb = 0; nb < 4; ++nb)
#pragma unroll
        for (int rj = 0; rj < 4; ++rj)
            rbuf[nb * 4 + rj] =
                relh[(size_t)(q0w + quad * 4 + rj) * Sc + nb * 16 + l15];

#pragma unroll
    for (int kt = 0; kt < 16; ++kt) {
        const int kbase = kt * 64;

        // ---- S = Q K^T -----------------------------------------------------
        f32x4 sc[4] = {};
#pragma unroll
        for (int nb = 0; nb < 4; ++nb) {
            const _Float16* kp = kh + (size_t)(kbase + nb * 16 + l15) * HDc + quad * 8;
            f16x8 kf0 = *(const f16x8*)kp;
            f16x8 kf1 = *(const f16x8*)(kp + 32);
            sc[nb] = MFMA16(qf0, kf0, sc[nb]);
            sc[nb] = MFMA16(qf1, kf1, sc[nb]);
        }

        // ---- prefetch rel tile kt+1 ---------------------------------------
        float rn[16];
        if (kt < 15) {
#pragma unroll
            for (int nb = 0; nb < 4; ++nb)
#pragma unroll
                for (int rj = 0; rj < 4; ++rj)
                    rn[nb * 4 + rj] =
                        relh[(size_t)(q0w + quad * 4 + rj) * Sc
                             + kbase + 64 + nb * 16 + l15];
        }

        // ---- scale + rel bias + mask (C layout: col=l15, row=quad*4+rj) ---
#pragma unroll
        for (int nb = 0; nb < 4; ++nb) {
            const float mk = maskb[kbase + nb * 16 + l15];
#pragma unroll
            for (int rj = 0; rj < 4; ++rj)
                sc[nb][rj] = sc[nb][rj] * 0.125f + rbuf[nb * 4 + rj] + mk;
        }

        // ---- online softmax (row lives on 16 lanes of one quad) -----------
#pragma unroll
        for (int rj = 0; rj < 4; ++rj) {
            float mx = fmaxf(fmaxf(sc[0][rj], sc[1][rj]), fmaxf(sc[2][rj], sc[3][rj]));
#pragma unroll
            for (int off = 1; off < 16; off <<= 1) mx = fmaxf(mx, __shfl_xor(mx, off));
            const float mnew  = fmaxf(m_run[rj], mx);
            const float alpha = __expf(m_run[rj] - mnew);
            float rs = 0.f;
#pragma unroll
            for (int nb = 0; nb < 4; ++nb) {
                const float p = __expf(sc[nb][rj] - mnew);
                sc[nb][rj] = p;
                rs += p;
            }
#pragma unroll
            for (int off = 1; off < 16; off <<= 1) rs += __shfl_xor(rs, off);
            m_run[rj] = mnew;
            l_run[rj] = l_run[rj] * alpha + rs;
            o[0][rj] *= alpha; o[1][rj] *= alpha; o[2][rj] *= alpha; o[3][rj] *= alpha;
        }

        // ---- P: C layout -> A layout via per-wave LDS (no barriers) -------
#pragma unroll
        for (int nb = 0; nb < 4; ++nb)
#pragma unroll
            for (int rj = 0; rj < 4; ++rj)
                lds_p[w][quad * 4 + rj][nb * 16 + l15] = (_Float16)sc[nb][rj];
        f16x8 ap0 = *(const f16x8*)&lds_p[w][l15][quad * 8];
        f16x8 ap1 = *(const f16x8*)&lds_p[w][l15][32 + quad * 8];

        // ---- O += P V  (B operand from V^T) -------------------------------
#pragma unroll
        for (int nb = 0; nb < 4; ++nb) {
            const _Float16* vp = vh + (size_t)(nb * 16 + l15) * Sc + kbase + quad * 8;
            f16x8 v0 = *(const f16x8*)vp;
            f16x8 v1 = *(const f16x8*)(vp + 32);
            o[nb] = MFMA16(ap0, v0, o[nb]);
            o[nb] = MFMA16(ap1, v1, o[nb]);
        }

#pragma unroll
        for (int i = 0; i < 16; ++i) rbuf[i] = rn[i];
    }

    // ---- epilogue ---------------------------------------------------------
#pragma unroll
    for (int rj = 0; rj < 4; ++rj) {
        const float linv = 1.0f / l_run[rj];
        const int qrow = q0w + quad * 4 + rj;
#pragma unroll
        for (int nb = 0; nb < 4; ++nb)
            out[((size_t)(b * Sc + qrow)) * Hc + h * HDc + nb * 16 + l15] =
                o[nb][rj] * linv;
    }
}

extern "C" void kernel_launch(void* const* d_in, const int* in_sizes, int n_in,
                              void* d_out, int out_size, void* d_ws, size_t ws_size,
                              hipStream_t stream) {
    const float* hs   = (const float*)d_in[0];
    const float* mask = (const float*)d_in[1];
    const float* rel  = (const float*)d_in[2];
    const float* Wq   = (const float*)d_in[3];
    const float* bq   = (const float*)d_in[4];
    const float* Wk   = (const float*)d_in[5];
    const float* bk   = (const float*)d_in[6];
    const float* Wv   = (const float*)d_in[7];
    const float* bv   = (const float*)d_in[8];
    float* out = (float*)d_out;

    const size_t elems = (size_t)Bc * Sc * Hc;        // 4,194,304
    _Float16* hs16 = (_Float16*)d_ws;                 // 8 MB
    _Float16* w16  = hs16 + elems;                    // 1.5 MB
    _Float16* qws  = w16 + (size_t)3 * Hc * Hc;       // 8 MB
    _Float16* kws  = qws + elems;                     // 8 MB
    _Float16* vws  = kws + elems;                     // 8 MB   (total ~33.5 MB)

    const int cvt_blocks = (int)(((size_t)Bc * Sc * Hc + 3 * Hc * Hc) / 4 / 256);
    cvt_f16<<<cvt_blocks, 256, 0, stream>>>(hs, Wq, Wk, Wv, hs16, w16);
    qkv_gemm<<<dim3(64, 12), 256, 0, stream>>>(hs16, w16, bq, bk, bv,
                                               qws, kws, vws);
    attn<<<dim3(16, 64), 256, 0, stream>>>(qws, kws, vws, rel, mask, out);
}

// Round 3
// 516.040 us; speedup vs baseline: 1.2421x; 1.2421x over previous
//
#include <hip/hip_runtime.h>

typedef _Float16 f16x8 __attribute__((ext_vector_type(8)));
typedef _Float16 f16x4 __attribute__((ext_vector_type(4)));
typedef float    f32x4 __attribute__((ext_vector_type(4)));

#define MFMA16(a,b,c) __builtin_amdgcn_mfma_f32_16x16x32_f16((a),(b),(c),0,0,0)

constexpr int Bc  = 8;
constexpr int Sc  = 1024;
constexpr int Hc  = 512;
constexpr int NHc = 8;
constexpr int HDc = 64;

// ---------------------------------------------------------------------------
// Stage 0: fp32 -> fp16 convert of hs and the three W matrices (concatenated).
// hs16: [8192][512], w16: [1536][512] (rows 0-511 Wq, 512-1023 Wk, 1024- Wv).
// ---------------------------------------------------------------------------
__global__ __launch_bounds__(256) void cvt_f16(
    const float* __restrict__ hs,
    const float* __restrict__ wq, const float* __restrict__ wk,
    const float* __restrict__ wv,
    _Float16* __restrict__ hs16, _Float16* __restrict__ w16)
{
    const size_t i4  = (size_t)blockIdx.x * 256 + threadIdx.x;  // float4 index
    const size_t HS4 = (size_t)Bc * Sc * Hc / 4;   // 1,048,576
    const size_t W4  = (size_t)Hc * Hc / 4;        // 65,536
    float4 v;
    _Float16* dst;
    if (i4 < HS4) {
        v = ((const float4*)hs)[i4];
        dst = hs16 + i4 * 4;
    } else {
        const size_t j = i4 - HS4;
        const int z = (int)(j / W4);
        const size_t o = j - (size_t)z * W4;
        const float* src = (z == 0) ? wq : (z == 1) ? wk : wv;
        v = ((const float4*)src)[o];
        dst = w16 + j * 4;
    }
    f16x4 h;
    h[0] = (_Float16)v.x; h[1] = (_Float16)v.y;
    h[2] = (_Float16)v.z; h[3] = (_Float16)v.w;
    *(f16x4*)dst = h;
}

// ---------------------------------------------------------------------------
// Stage 1: fused QKV GEMM, m97-style. C[m][n] = hs16[m][:] . w16[n][:] + b[n]
// M=8192, N=1536, K=512. 128x128 tiles, BK=64, global_load_lds width-16.
// Q,K -> [BH][S][64] fp16;  V -> transposed [BH][64][S] fp16.
// (unchanged from round 2 so its true duration surfaces in the top-5)
// ---------------------------------------------------------------------------
__global__ __launch_bounds__(256) void qkv_gemm(
    const _Float16* __restrict__ A,   // [8192][512]
    const _Float16* __restrict__ Bm,  // [1536][512]
    const float* __restrict__ bq, const float* __restrict__ bk,
    const float* __restrict__ bv,
    _Float16* __restrict__ qws, _Float16* __restrict__ kws,
    _Float16* __restrict__ vws)
{
    __shared__ __align__(16) _Float16 As[128 * 64];
    __shared__ __align__(16) _Float16 Bs[128 * 64];

    const int m0 = blockIdx.x * 128;   // 64
    const int n0 = blockIdx.y * 128;   // 12
    const int tid  = threadIdx.x;
    const int lane = tid & 63;
    const int w    = tid >> 6;
    const int l15  = lane & 15;
    const int quad = lane >> 4;
    const int wm   = (w >> 1) * 64;
    const int wn   = (w & 1) * 64;

    f32x4 acc[4][4] = {};

    const int srow = tid >> 3;         // 0..31
    const int scol = (tid & 7) * 8;    // fp16 units

    for (int k0 = 0; k0 < 512; k0 += 64) {
        __syncthreads();               // WAR: frag reads of prev tile done
#pragma unroll
        for (int j = 0; j < 4; ++j) {
            const _Float16* ga = A  + (size_t)(m0 + srow + 32 * j) * 512 + k0 + scol;
            const _Float16* gb = Bm + (size_t)(n0 + srow + 32 * j) * 512 + k0 + scol;
            __builtin_amdgcn_global_load_lds(
                (const __attribute__((address_space(1))) void*)ga,
                (__attribute__((address_space(3))) void*)(As + tid * 8 + j * 2048),
                16, 0, 0);
            __builtin_amdgcn_global_load_lds(
                (const __attribute__((address_space(1))) void*)gb,
                (__attribute__((address_space(3))) void*)(Bs + tid * 8 + j * 2048),
                16, 0, 0);
        }
        __syncthreads();               // RAW: vmcnt(0) drained before barrier
#pragma unroll
        for (int ks = 0; ks < 2; ++ks) {
            f16x8 af[4], bf[4];
#pragma unroll
            for (int i = 0; i < 4; ++i) {
                af[i] = *(const f16x8*)&As[(wm + i * 16 + l15) * 64 + ks * 32 + quad * 8];
                bf[i] = *(const f16x8*)&Bs[(wn + i * 16 + l15) * 64 + ks * 32 + quad * 8];
            }
#pragma unroll
            for (int mb = 0; mb < 4; ++mb)
#pragma unroll
                for (int nb = 0; nb < 4; ++nb)
                    acc[mb][nb] = MFMA16(af[mb], bf[nb], acc[mb][nb]);
        }
    }

    // Epilogue. zsel uniform per block (128 | 512).
    const int zsel = n0 >> 9;
    const float* bias = (zsel == 0) ? bq : (zsel == 1) ? bk : bv;
#pragma unroll
    for (int nb = 0; nb < 4; ++nb) {
        const int n  = n0 + wn + nb * 16 + l15;
        const int nn = n & 511;
        const int h  = nn >> 6;
        const int hd = nn & 63;
        const float bvv = bias[nn];
#pragma unroll
        for (int mb = 0; mb < 4; ++mb) {
            const int m = m0 + wm + mb * 16 + quad * 4;   // +rr, rr=0..3
            const int b = m >> 10;
            const int s = m & 1023;
            if (zsel == 2) {
                f16x4 t;
#pragma unroll
                for (int rr = 0; rr < 4; ++rr)
                    t[rr] = (_Float16)(acc[mb][nb][rr] + bvv);
                *(f16x4*)&vws[((size_t)(b * NHc + h) * HDc + hd) * Sc + s] = t;
            } else {
                _Float16* dst = (zsel == 0 ? qws : kws)
                              + ((size_t)(b * NHc + h) * Sc + s) * HDc + hd;
#pragma unroll
                for (int rr = 0; rr < 4; ++rr)
                    dst[(size_t)rr * HDc] = (_Float16)(acc[mb][nb][rr] + bvv);
            }
        }
    }
}

// ---------------------------------------------------------------------------
// Stage 2: flash attention with rel_2d_pos bias + additive mask.
// v3: 128-thread blocks (2 waves x 16 q-rows), grid (32,64) = 2048 blocks for
// TLP; NO barriers (per-wave LDS P slice); NO register prefetch / no kt
// unroll (keep VGPR ~72 so ~20+ waves/CU hide the rel-stream HBM latency).
// ---------------------------------------------------------------------------
__global__ __launch_bounds__(128) void attn(
    const _Float16* __restrict__ qws, const _Float16* __restrict__ kws,
    const _Float16* __restrict__ vws, const float* __restrict__ rel,
    const float* __restrict__ mask, float* __restrict__ out)
{
    const int qt = blockIdx.x;      // 0..31 (32 q-rows per block)
    const int bh = blockIdx.y;      // 0..63
    const int b  = bh >> 3;
    const int h  = bh & 7;
    const int tid  = threadIdx.x;
    const int w    = tid >> 6;      // 0..1
    const int lane = tid & 63;
    const int l15  = lane & 15;
    const int quad = lane >> 4;
    const int q0w  = qt * 32 + w * 16;

    __shared__ __align__(16) _Float16 lds_p[2][16][72];  // per-wave slice

    const _Float16* qh = qws + (size_t)bh * Sc * HDc;
    const _Float16* kh = kws + (size_t)bh * Sc * HDc;
    const _Float16* vh = vws + (size_t)bh * HDc * Sc;
    const float* relh  = rel + (size_t)bh * Sc * Sc;
    const float* maskb = mask + (size_t)b * Sc;

    f16x8 qf0 = *(const f16x8*)(qh + (size_t)(q0w + l15) * HDc + quad * 8);
    f16x8 qf1 = *(const f16x8*)(qh + (size_t)(q0w + l15) * HDc + 32 + quad * 8);

    float m_run[4], l_run[4];
    f32x4 o[4] = {};
#pragma unroll
    for (int rj = 0; rj < 4; ++rj) { m_run[rj] = -1e30f; l_run[rj] = 0.f; }

    for (int kt = 0; kt < 16; ++kt) {
        const int kbase = kt * 64;

        // ---- S = Q K^T -----------------------------------------------------
        f32x4 sc[4] = {};
#pragma unroll
        for (int nb = 0; nb < 4; ++nb) {
            const _Float16* kp = kh + (size_t)(kbase + nb * 16 + l15) * HDc + quad * 8;
            f16x8 kf0 = *(const f16x8*)kp;
            f16x8 kf1 = *(const f16x8*)(kp + 32);
            sc[nb] = MFMA16(qf0, kf0, sc[nb]);
            sc[nb] = MFMA16(qf1, kf1, sc[nb]);
        }

        // ---- scale + rel bias + mask (C layout: col=l15, row=quad*4+rj) ---
#pragma unroll
        for (int nb = 0; nb < 4; ++nb) {
            const int kcol = kbase + nb * 16 + l15;
            const float mk = maskb[kcol];
#pragma unroll
            for (int rj = 0; rj < 4; ++rj) {
                const int qrow = q0w + quad * 4 + rj;
                sc[nb][rj] = sc[nb][rj] * 0.125f + relh[(size_t)qrow * Sc + kcol] + mk;
            }
        }

        // ---- online softmax (row lives on 16 lanes of one quad) -----------
#pragma unroll
        for (int rj = 0; rj < 4; ++rj) {
            float mx = fmaxf(fmaxf(sc[0][rj], sc[1][rj]), fmaxf(sc[2][rj], sc[3][rj]));
#pragma unroll
            for (int off = 1; off < 16; off <<= 1) mx = fmaxf(mx, __shfl_xor(mx, off));
            const float mnew  = fmaxf(m_run[rj], mx);
            const float alpha = __expf(m_run[rj] - mnew);
            float rs = 0.f;
#pragma unroll
            for (int nb = 0; nb < 4; ++nb) {
                const float p = __expf(sc[nb][rj] - mnew);
                sc[nb][rj] = p;
                rs += p;
            }
#pragma unroll
            for (int off = 1; off < 16; off <<= 1) rs += __shfl_xor(rs, off);
            m_run[rj] = mnew;
            l_run[rj] = l_run[rj] * alpha + rs;
            o[0][rj] *= alpha; o[1][rj] *= alpha; o[2][rj] *= alpha; o[3][rj] *= alpha;
        }

        // ---- P: C layout -> A layout via per-wave LDS (no barriers) -------
#pragma unroll
        for (int nb = 0; nb < 4; ++nb)
#pragma unroll
            for (int rj = 0; rj < 4; ++rj)
                lds_p[w][quad * 4 + rj][nb * 16 + l15] = (_Float16)sc[nb][rj];
        f16x8 ap0 = *(const f16x8*)&lds_p[w][l15][quad * 8];
        f16x8 ap1 = *(const f16x8*)&lds_p[w][l15][32 + quad * 8];

        // ---- O += P V  (B operand from V^T) -------------------------------
#pragma unroll
        for (int nb = 0; nb < 4; ++nb) {
            const _Float16* vp = vh + (size_t)(nb * 16 + l15) * Sc + kbase + quad * 8;
            f16x8 v0 = *(const f16x8*)vp;
            f16x8 v1 = *(const f16x8*)(vp + 32);
            o[nb] = MFMA16(ap0, v0, o[nb]);
            o[nb] = MFMA16(ap1, v1, o[nb]);
        }
    }

    // ---- epilogue ---------------------------------------------------------
#pragma unroll
    for (int rj = 0; rj < 4; ++rj) {
        const float linv = 1.0f / l_run[rj];
        const int qrow = q0w + quad * 4 + rj;
#pragma unroll
        for (int nb = 0; nb < 4; ++nb)
            out[((size_t)(b * Sc + qrow)) * Hc + h * HDc + nb * 16 + l15] =
                o[nb][rj] * linv;
    }
}

extern "C" void kernel_launch(void* const* d_in, const int* in_sizes, int n_in,
                              void* d_out, int out_size, void* d_ws, size_t ws_size,
                              hipStream_t stream) {
    const float* hs   = (const float*)d_in[0];
    const float* mask = (const float*)d_in[1];
    const float* rel  = (const float*)d_in[2];
    const float* Wq   = (const float*)d_in[3];
    const float* bq   = (const float*)d_in[4];
    const float* Wk   = (const float*)d_in[5];
    const float* bk   = (const float*)d_in[6];
    const float* Wv   = (const float*)d_in[7];
    const float* bv   = (const float*)d_in[8];
    float* out = (float*)d_out;

    const size_t elems = (size_t)Bc * Sc * Hc;        // 4,194,304
    _Float16* hs16 = (_Float16*)d_ws;                 // 8 MB
    _Float16* w16  = hs16 + elems;                    // 1.5 MB
    _Float16* qws  = w16 + (size_t)3 * Hc * Hc;       // 8 MB
    _Float16* kws  = qws + elems;                     // 8 MB
    _Float16* vws  = kws + elems;                     // 8 MB   (total ~33.5 MB)

    const int cvt_blocks = (int)(((size_t)Bc * Sc * Hc + 3 * Hc * Hc) / 4 / 256);
    cvt_f16<<<cvt_blocks, 256, 0, stream>>>(hs, Wq, Wk, Wv, hs16, w16);
    qkv_gemm<<<dim3(64, 12), 256, 0, stream>>>(hs16, w16, bq, bk, bv,
                                               qws, kws, vws);
    attn<<<dim3(32, 64), 128, 0, stream>>>(qws, kws, vws, rel, mask, out);
}

// Round 4
// 486.225 us; speedup vs baseline: 1.3182x; 1.0613x over previous
//
#include <hip/hip_runtime.h>

typedef _Float16 f16x8 __attribute__((ext_vector_type(8)));
typedef _Float16 f16x4 __attribute__((ext_vector_type(4)));
typedef float    f32x4 __attribute__((ext_vector_type(4)));

#define MFMA16(a,b,c) __builtin_amdgcn_mfma_f32_16x16x32_f16((a),(b),(c),0,0,0)

constexpr int Bc  = 8;
constexpr int Sc  = 1024;
constexpr int Hc  = 512;
constexpr int NHc = 8;
constexpr int HDc = 64;

// ---------------------------------------------------------------------------
// Stage 0: fp32 -> fp16 convert of hs and the three W matrices (concatenated).
// ---------------------------------------------------------------------------
__global__ __launch_bounds__(256) void cvt_f16(
    const float* __restrict__ hs,
    const float* __restrict__ wq, const float* __restrict__ wk,
    const float* __restrict__ wv,
    _Float16* __restrict__ hs16, _Float16* __restrict__ w16)
{
    const size_t i4  = (size_t)blockIdx.x * 256 + threadIdx.x;  // float4 index
    const size_t HS4 = (size_t)Bc * Sc * Hc / 4;   // 1,048,576
    const size_t W4  = (size_t)Hc * Hc / 4;        // 65,536
    float4 v;
    _Float16* dst;
    if (i4 < HS4) {
        v = ((const float4*)hs)[i4];
        dst = hs16 + i4 * 4;
    } else {
        const size_t j = i4 - HS4;
        const int z = (int)(j / W4);
        const size_t o = j - (size_t)z * W4;
        const float* src = (z == 0) ? wq : (z == 1) ? wk : wv;
        v = ((const float4*)src)[o];
        dst = w16 + j * 4;
    }
    f16x4 h;
    h[0] = (_Float16)v.x; h[1] = (_Float16)v.y;
    h[2] = (_Float16)v.z; h[3] = (_Float16)v.w;
    *(f16x4*)dst = h;
}

// ---------------------------------------------------------------------------
// Stage 1: fused QKV GEMM, m97-style (unchanged).
// ---------------------------------------------------------------------------
__global__ __launch_bounds__(256) void qkv_gemm(
    const _Float16* __restrict__ A,   // [8192][512]
    const _Float16* __restrict__ Bm,  // [1536][512]
    const float* __restrict__ bq, const float* __restrict__ bk,
    const float* __restrict__ bv,
    _Float16* __restrict__ qws, _Float16* __restrict__ kws,
    _Float16* __restrict__ vws)
{
    __shared__ __align__(16) _Float16 As[128 * 64];
    __shared__ __align__(16) _Float16 Bs[128 * 64];

    const int m0 = blockIdx.x * 128;
    const int n0 = blockIdx.y * 128;
    const int tid  = threadIdx.x;
    const int lane = tid & 63;
    const int w    = tid >> 6;
    const int l15  = lane & 15;
    const int quad = lane >> 4;
    const int wm   = (w >> 1) * 64;
    const int wn   = (w & 1) * 64;

    f32x4 acc[4][4] = {};

    const int srow = tid >> 3;
    const int scol = (tid & 7) * 8;

    for (int k0 = 0; k0 < 512; k0 += 64) {
        __syncthreads();
#pragma unroll
        for (int j = 0; j < 4; ++j) {
            const _Float16* ga = A  + (size_t)(m0 + srow + 32 * j) * 512 + k0 + scol;
            const _Float16* gb = Bm + (size_t)(n0 + srow + 32 * j) * 512 + k0 + scol;
            __builtin_amdgcn_global_load_lds(
                (const __attribute__((address_space(1))) void*)ga,
                (__attribute__((address_space(3))) void*)(As + tid * 8 + j * 2048),
                16, 0, 0);
            __builtin_amdgcn_global_load_lds(
                (const __attribute__((address_space(1))) void*)gb,
                (__attribute__((address_space(3))) void*)(Bs + tid * 8 + j * 2048),
                16, 0, 0);
        }
        __syncthreads();
#pragma unroll
        for (int ks = 0; ks < 2; ++ks) {
            f16x8 af[4], bf[4];
#pragma unroll
            for (int i = 0; i < 4; ++i) {
                af[i] = *(const f16x8*)&As[(wm + i * 16 + l15) * 64 + ks * 32 + quad * 8];
                bf[i] = *(const f16x8*)&Bs[(wn + i * 16 + l15) * 64 + ks * 32 + quad * 8];
            }
#pragma unroll
            for (int mb = 0; mb < 4; ++mb)
#pragma unroll
                for (int nb = 0; nb < 4; ++nb)
                    acc[mb][nb] = MFMA16(af[mb], bf[nb], acc[mb][nb]);
        }
    }

    const int zsel = n0 >> 9;
    const float* bias = (zsel == 0) ? bq : (zsel == 1) ? bk : bv;
#pragma unroll
    for (int nb = 0; nb < 4; ++nb) {
        const int n  = n0 + wn + nb * 16 + l15;
        const int nn = n & 511;
        const int h  = nn >> 6;
        const int hd = nn & 63;
        const float bvv = bias[nn];
#pragma unroll
        for (int mb = 0; mb < 4; ++mb) {
            const int m = m0 + wm + mb * 16 + quad * 4;
            const int b = m >> 10;
            const int s = m & 1023;
            if (zsel == 2) {
                f16x4 t;
#pragma unroll
                for (int rr = 0; rr < 4; ++rr)
                    t[rr] = (_Float16)(acc[mb][nb][rr] + bvv);
                *(f16x4*)&vws[((size_t)(b * NHc + h) * HDc + hd) * Sc + s] = t;
            } else {
                _Float16* dst = (zsel == 0 ? qws : kws)
                              + ((size_t)(b * NHc + h) * Sc + s) * HDc + hd;
#pragma unroll
                for (int rr = 0; rr < 4; ++rr)
                    dst[(size_t)rr * HDc] = (_Float16)(acc[mb][nb][rr] + bvv);
            }
        }
    }
}

// ---------------------------------------------------------------------------
// Stage 2: flash attention. v4: same 2-wave/128-thread barrier-free structure
// as v3, but (a) __launch_bounds__(128,4) caps occupancy at 4 waves/EU
// (= the grid's own 16 waves/CU ceiling, so nothing is lost) to give the
// scheduler a 128-VGPR budget, and (b) all 16 rel loads + 8 K-frag loads are
// hoisted to the top of each k-tile iteration so they are ALL in flight while
// the QK MFMAs run. v3's 64-VGPR allocation serialized the rel loads
// (~1 outstanding 256B load/wave -> 1.27 TB/s).
// ---------------------------------------------------------------------------
__global__ __launch_bounds__(128, 4) void attn(
    const _Float16* __restrict__ qws, const _Float16* __restrict__ kws,
    const _Float16* __restrict__ vws, const float* __restrict__ rel,
    const float* __restrict__ mask, float* __restrict__ out)
{
    const int qt = blockIdx.x;      // 0..31 (32 q-rows per block)
    const int bh = blockIdx.y;      // 0..63
    const int b  = bh >> 3;
    const int h  = bh & 7;
    const int tid  = threadIdx.x;
    const int w    = tid >> 6;      // 0..1
    const int lane = tid & 63;
    const int l15  = lane & 15;
    const int quad = lane >> 4;
    const int q0w  = qt * 32 + w * 16;

    __shared__ __align__(16) _Float16 lds_p[2][16][72];  // per-wave slice

    const _Float16* qh = qws + (size_t)bh * Sc * HDc;
    const _Float16* kh = kws + (size_t)bh * Sc * HDc;
    const _Float16* vh = vws + (size_t)bh * HDc * Sc;
    const float* relh  = rel + (size_t)bh * Sc * Sc;
    const float* maskb = mask + (size_t)b * Sc;

    f16x8 qf0 = *(const f16x8*)(qh + (size_t)(q0w + l15) * HDc + quad * 8);
    f16x8 qf1 = *(const f16x8*)(qh + (size_t)(q0w + l15) * HDc + 32 + quad * 8);

    float m_run[4], l_run[4];
    f32x4 o[4] = {};
#pragma unroll
    for (int rj = 0; rj < 4; ++rj) { m_run[rj] = -1e30f; l_run[rj] = 0.f; }

    // lane's base into its rel rows: row = q0w + quad*4 (+rj), col base l15
    const float* relp = relh + (size_t)(q0w + quad * 4) * Sc + l15;

#pragma unroll 2
    for (int kt = 0; kt < 16; ++kt) {
        const int kbase = kt * 64;

        // ---- issue ALL independent loads for this tile up front -----------
        float rb[16];
#pragma unroll
        for (int nb = 0; nb < 4; ++nb)
#pragma unroll
            for (int rj = 0; rj < 4; ++rj)
                rb[nb * 4 + rj] = relp[(size_t)rj * Sc + kbase + nb * 16];

        f16x8 kf0[4], kf1[4];
#pragma unroll
        for (int nb = 0; nb < 4; ++nb) {
            const _Float16* kp = kh + (size_t)(kbase + nb * 16 + l15) * HDc + quad * 8;
            kf0[nb] = *(const f16x8*)kp;
            kf1[nb] = *(const f16x8*)(kp + 32);
        }

        // ---- S = Q K^T (overlaps the rel-load latency) ---------------------
        f32x4 sc[4] = {};
#pragma unroll
        for (int nb = 0; nb < 4; ++nb) {
            sc[nb] = MFMA16(qf0, kf0[nb], sc[nb]);
            sc[nb] = MFMA16(qf1, kf1[nb], sc[nb]);
        }

        // ---- scale + rel bias + mask (C layout: col=l15, row=quad*4+rj) ---
#pragma unroll
        for (int nb = 0; nb < 4; ++nb) {
            const float mk = maskb[kbase + nb * 16 + l15];
#pragma unroll
            for (int rj = 0; rj < 4; ++rj)
                sc[nb][rj] = sc[nb][rj] * 0.125f + rb[nb * 4 + rj] + mk;
        }

        // ---- online softmax (row lives on 16 lanes of one quad) -----------
#pragma unroll
        for (int rj = 0; rj < 4; ++rj) {
            float mx = fmaxf(fmaxf(sc[0][rj], sc[1][rj]), fmaxf(sc[2][rj], sc[3][rj]));
#pragma unroll
            for (int off = 1; off < 16; off <<= 1) mx = fmaxf(mx, __shfl_xor(mx, off));
            const float mnew  = fmaxf(m_run[rj], mx);
            const float alpha = __expf(m_run[rj] - mnew);
            float rs = 0.f;
#pragma unroll
            for (int nb = 0; nb < 4; ++nb) {
                const float p = __expf(sc[nb][rj] - mnew);
                sc[nb][rj] = p;
                rs += p;
            }
#pragma unroll
            for (int off = 1; off < 16; off <<= 1) rs += __shfl_xor(rs, off);
            m_run[rj] = mnew;
            l_run[rj] = l_run[rj] * alpha + rs;
            o[0][rj] *= alpha; o[1][rj] *= alpha; o[2][rj] *= alpha; o[3][rj] *= alpha;
        }

        // ---- P: C layout -> A layout via per-wave LDS (no barriers) -------
#pragma unroll
        for (int nb = 0; nb < 4; ++nb)
#pragma unroll
            for (int rj = 0; rj < 4; ++rj)
                lds_p[w][quad * 4 + rj][nb * 16 + l15] = (_Float16)sc[nb][rj];
        f16x8 ap0 = *(const f16x8*)&lds_p[w][l15][quad * 8];
        f16x8 ap1 = *(const f16x8*)&lds_p[w][l15][32 + quad * 8];

        // ---- O += P V  (B operand from V^T) -------------------------------
#pragma unroll
        for (int nb = 0; nb < 4; ++nb) {
            const _Float16* vp = vh + (size_t)(nb * 16 + l15) * Sc + kbase + quad * 8;
            f16x8 v0 = *(const f16x8*)vp;
            f16x8 v1 = *(const f16x8*)(vp + 32);
            o[nb] = MFMA16(ap0, v0, o[nb]);
            o[nb] = MFMA16(ap1, v1, o[nb]);
        }
    }

    // ---- epilogue ---------------------------------------------------------
#pragma unroll
    for (int rj = 0; rj < 4; ++rj) {
        const float linv = 1.0f / l_run[rj];
        const int qrow = q0w + quad * 4 + rj;
#pragma unroll
        for (int nb = 0; nb < 4; ++nb)
            out[((size_t)(b * Sc + qrow)) * Hc + h * HDc + nb * 16 + l15] =
                o[nb][rj] * linv;
    }
}

extern "C" void kernel_launch(void* const* d_in, const int* in_sizes, int n_in,
                              void* d_out, int out_size, void* d_ws, size_t ws_size,
                              hipStream_t stream) {
    const float* hs   = (const float*)d_in[0];
    const float* mask = (const float*)d_in[1];
    const float* rel  = (const float*)d_in[2];
    const float* Wq   = (const float*)d_in[3];
    const float* bq   = (const float*)d_in[4];
    const float* Wk   = (const float*)d_in[5];
    const float* bk   = (const float*)d_in[6];
    const float* Wv   = (const float*)d_in[7];
    const float* bv   = (const float*)d_in[8];
    float* out = (float*)d_out;

    const size_t elems = (size_t)Bc * Sc * Hc;        // 4,194,304
    _Float16* hs16 = (_Float16*)d_ws;                 // 8 MB
    _Float16* w16  = hs16 + elems;                    // 1.5 MB
    _Float16* qws  = w16 + (size_t)3 * Hc * Hc;       // 8 MB
    _Float16* kws  = qws + elems;                     // 8 MB
    _Float16* vws  = kws + elems;                     // 8 MB   (total ~33.5 MB)

    const int cvt_blocks = (int)(((size_t)Bc * Sc * Hc + 3 * Hc * Hc) / 4 / 256);
    cvt_f16<<<cvt_blocks, 256, 0, stream>>>(hs, Wq, Wk, Wv, hs16, w16);
    qkv_gemm<<<dim3(64, 12), 256, 0, stream>>>(hs16, w16, bq, bk, bv,
                                               qws, kws, vws);
    attn<<<dim3(32, 64), 128, 0, stream>>>(qws, kws, vws, rel, mask, out);
}